// Round 1
// baseline (323.319 us; speedup 1.0000x reference)
//
#include <hip/hip_runtime.h>

#define ZD 64
#define RD 128
#define HIDDEN 512
#define NSTEP 100
#define OUT_PITCH 6464              // 101*64
#define DT_F 0.01f

static const size_t LW_OFF = 52953088ull;   // 8192*101*64
static const size_t NG_OFF = 52961280ull;   // + 8192

typedef __attribute__((ext_vector_type(4))) float  f32x4;
typedef __attribute__((ext_vector_type(8))) __bf16 bf16x8;
typedef __attribute__((ext_vector_type(4))) short  s16x4;
typedef __attribute__((ext_vector_type(8))) short  s16x8;

__device__ __forceinline__ short f2bs(float f) {
    return __builtin_bit_cast(short, (__bf16)f);
}
__device__ __forceinline__ float tanh_fast(float x) {
    // tanh(x) = 1 - 2/(exp2(x*2*log2e)+1); exp2/rcp are 1-ulp HW ops
    float e = __builtin_amdgcn_exp2f(x * 2.88539008177793f);
    float r = __builtin_amdgcn_rcpf(e + 1.0f);
    return fmaf(-2.0f, r, 1.0f);
}

// ---------------------------------------------------------------------------
// pre_kernel: pre[b][n] = b1[n] + sum_k r[b][k] * W1[64+k][n]
// stored into d_out at x_t[b][1..9) region (read by sim_kernel init, then
// overwritten by steps 1..8 of the main loop).
// ---------------------------------------------------------------------------
__global__ __launch_bounds__(256) void pre_kernel(
    const float* __restrict__ r, const float* __restrict__ W1,
    const float* __restrict__ b1, float* __restrict__ out)
{
    __shared__ float rt[32 * 128];
    const int tid = threadIdx.x;
    const int row0 = blockIdx.x * 32;
    #pragma unroll
    for (int i = 0; i < 16; ++i) {
        int e = tid + i * 256;
        rt[e] = r[(size_t)row0 * RD + e];
    }
    __syncthreads();
    float acc0[32], acc1[32];
    #pragma unroll
    for (int rr = 0; rr < 32; ++rr) { acc0[rr] = 0.f; acc1[rr] = 0.f; }
    const int c0 = tid, c1 = tid + 256;
    for (int k = 0; k < RD; ++k) {
        float w0 = W1[(size_t)(64 + k) * HIDDEN + c0];
        float w1v = W1[(size_t)(64 + k) * HIDDEN + c1];
        #pragma unroll
        for (int rr = 0; rr < 32; ++rr) {
            float rv = rt[rr * 128 + k];
            acc0[rr] = fmaf(rv, w0, acc0[rr]);
            acc1[rr] = fmaf(rv, w1v, acc1[rr]);
        }
    }
    float bb0 = b1[c0], bb1 = b1[c1];
    for (int rr = 0; rr < 32; ++rr) {
        out[(size_t)(row0 + rr) * OUT_PITCH + 64 + c0] = acc0[rr] + bb0;
        out[(size_t)(row0 + rr) * OUT_PITCH + 64 + c1] = acc1[rr] + bb1;
    }
}

// ---------------------------------------------------------------------------
// sim_kernel: persistent per-block scan. 256 blocks x 512 threads (8 waves),
// 32 rows per block. Weights as persistent register MFMA fragments.
// GEMMs computed transposed: D[row=n][col=m] so each lane's 4 outputs are
// contiguous in the n (=next K) dimension.
// ---------------------------------------------------------------------------
__global__ __launch_bounds__(512, 2) void sim_kernel(
    const float* __restrict__ noises, const float* __restrict__ x0,
    const float* __restrict__ W1, const float* __restrict__ W2,
    const float* __restrict__ b2, const float* __restrict__ bmax,
    const float* __restrict__ bmin, const float* __restrict__ mu,
    float* __restrict__ out)
{
    extern __shared__ char smem_raw[];
    float* Xf = (float*)smem_raw;                     // [32][68] f32 (padded)
    float* Ss = Xf + 32 * 68;                          // [32][68] f32 (padded)
    unsigned short* Hs = (unsigned short*)(Ss + 32 * 68); // [32*512] bf16 swizzled
    float* w1ts = (float*)(Hs + 32 * HIDDEN);          // [512]
    float* mus  = w1ts + HIDDEN;                       // [64]
    float* tT  = mus + 64;                             // [128] each
    float* tG  = tT + 128;
    float* tSd = tG + 128;
    float* tCd = tSd + 128;
    float* tCs = tCd + 128;

    const int tid  = threadIdx.x;
    const int lane = tid & 63;
    const int wave = tid >> 6;
    const int g4   = lane >> 4;     // 0..3
    const int l16  = lane & 15;
    const int row0 = blockIdx.x * 32;

    // ---- step tables (mirrors the JAX schedule math in f32) ----
    if (tid < NSTEP) {
        float spmax = log1pf(expf(bmax[0]));
        float spmin = log1pf(expf(bmin[0]));
        float a_ = spmax - spmin;
        float c_ = spmin;
        const float PI_ = 3.14159265358979323846f;
        float k = (float)tid;
        float t0 = k * DT_F, t1 = (k + 1.0f) * DT_F;
        float inv2pi = 1.0f / (2.0f * PI_);
        float F0 = a_ * sinf(PI_ * t0) * inv2pi + (0.5f * a_ + c_) * t0;
        float F1 = a_ * sinf(PI_ * t1) * inv2pi + (0.5f * a_ + c_) * t1;
        float al = 1.0f - expf(-2.0f * (F1 - F0));
        float gg = 1.0f - sqrtf(1.0f - al);
        float kap = (gg * gg) / al;
        tT[tid] = t0; tG[tid] = gg; tSd[tid] = sqrtf(al);
        tCd[tid] = -2.0f * kap; tCs[tid] = -2.0f * sqrtf(kap);
    }
    if (tid < HIDDEN) w1ts[tid] = W1[(size_t)192 * HIDDEN + tid];
    if (tid < ZD) mus[tid] = mu[tid];

    // ---- x state init + x_t[:,0,:] ----
    {
        int m = tid >> 4;
        int k4 = (tid & 15) << 2;
        f32x4 v = *(const f32x4*)(x0 + (size_t)(row0 + m) * ZD + k4);
        *(f32x4*)(Xf + m * 68 + k4) = v;
        *(f32x4*)(out + (size_t)(row0 + m) * OUT_PITCH + k4) = v;
    }

    // ---- persistent weight fragments (registers, step-invariant) ----
    // GEMM1 A-frags: A[n][k] = W1[k][n], n-tile NT = wave*4+j2, K=64 (2 chunks)
    bf16x8 w1f[4][2];
    #pragma unroll
    for (int j2 = 0; j2 < 4; ++j2) {
        int n = (wave * 4 + j2) * 16 + l16;
        #pragma unroll
        for (int kc = 0; kc < 2; ++kc) {
            bf16x8 v;
            #pragma unroll
            for (int j = 0; j < 8; ++j) {
                int kk = kc * 32 + g4 * 8 + j;
                v[j] = (__bf16)W1[(size_t)kk * HIDDEN + n];
            }
            w1f[j2][kc] = v;
        }
    }
    // GEMM2 A-frags: A[n][k] = W2[k][n], wave -> (mt = wave&1, nt = wave>>1)
    const int ntW = wave >> 1, mtW = wave & 1;
    bf16x8 w2f[16];
    {
        int n = ntW * 16 + l16;
        #pragma unroll
        for (int kc = 0; kc < 16; ++kc) {
            bf16x8 v;
            #pragma unroll
            for (int j = 0; j < 8; ++j) {
                int kk = kc * 32 + g4 * 8 + j;
                v[j] = (__bf16)W2[(size_t)kk * ZD + n];
            }
            w2f[kc] = v;
        }
    }
    float b2v = b2[ntW * 16 + l16];

    // ---- pre-fragments (written by pre_kernel into out) ----
    f32x4 pref[2][4];
    #pragma unroll
    for (int mt = 0; mt < 2; ++mt)
        #pragma unroll
        for (int j2 = 0; j2 < 4; ++j2) {
            int m = mt * 16 + l16;
            int n0 = (wave * 4 + j2) * 16 + g4 * 4;
            pref[mt][j2] = *(const f32x4*)(out + (size_t)(row0 + m) * OUT_PITCH + 64 + n0);
        }

    const int urow = tid >> 4;
    const int ui = (tid & 15) << 2;
    const size_t ubase = (size_t)(row0 + urow);
    float lw_acc = 0.0f;

    __syncthreads();

    for (int s = 0; s < NSTEP; ++s) {
        float t = tT[s], gg = tG[s], sdv = tSd[s], cd = tCd[s], cs = tCs[s];
        // prefetch noise for the U phase (2 barriers of latency hiding)
        f32x4 nz = *(const f32x4*)(noises + (ubase * NSTEP + s) * ZD + ui);

        // ================= GEMM1: h = tanh(x@W1x + pre + t*w1t) ============
        bf16x8 xb[2][2];   // B-frags: B[k][m] = X[m][k]
        #pragma unroll
        for (int mt = 0; mt < 2; ++mt)
            #pragma unroll
            for (int kc = 0; kc < 2; ++kc) {
                const float* p = Xf + (mt * 16 + l16) * 68 + kc * 32 + g4 * 8;
                f32x4 lo = *(const f32x4*)p;
                f32x4 hi = *(const f32x4*)(p + 4);
                bf16x8 v;
                v[0]=(__bf16)lo[0]; v[1]=(__bf16)lo[1]; v[2]=(__bf16)lo[2]; v[3]=(__bf16)lo[3];
                v[4]=(__bf16)hi[0]; v[5]=(__bf16)hi[1]; v[6]=(__bf16)hi[2]; v[7]=(__bf16)hi[3];
                xb[mt][kc] = v;
            }

        #pragma unroll
        for (int j2 = 0; j2 < 4; ++j2) {
            int n0 = (wave * 4 + j2) * 16 + g4 * 4;
            f32x4 wt = *(const f32x4*)(w1ts + n0);
            #pragma unroll
            for (int mt = 0; mt < 2; ++mt) {
                f32x4 acc = pref[mt][j2];
                acc[0] = fmaf(t, wt[0], acc[0]);
                acc[1] = fmaf(t, wt[1], acc[1]);
                acc[2] = fmaf(t, wt[2], acc[2]);
                acc[3] = fmaf(t, wt[3], acc[3]);
                acc = __builtin_amdgcn_mfma_f32_16x16x32_bf16(w1f[j2][0], xb[mt][0], acc, 0, 0, 0);
                acc = __builtin_amdgcn_mfma_f32_16x16x32_bf16(w1f[j2][1], xb[mt][1], acc, 0, 0, 0);
                s16x4 hv;
                hv[0] = f2bs(tanh_fast(acc[0]));
                hv[1] = f2bs(tanh_fast(acc[1]));
                hv[2] = f2bs(tanh_fast(acc[2]));
                hv[3] = f2bs(tanh_fast(acc[3]));
                int m = mt * 16 + l16;                  // D col = batch row
                int idx = (m * HIDDEN + n0) ^ ((m & 7) << 3);
                *(s16x4*)(Hs + idx) = hv;
            }
        }
        __syncthreads();

        // ================= GEMM2: score = h@W2 + b2 ========================
        {
            int m = mtW * 16 + l16;
            int swz = (m & 7) << 3;
            f32x4 acc2 = { b2v, b2v, b2v, b2v };
            f32x4 acc3 = { 0.f, 0.f, 0.f, 0.f };
            #pragma unroll
            for (int kc = 0; kc < 16; kc += 2) {
                s16x8 h0 = *(const s16x8*)(Hs + ((m * HIDDEN + kc * 32 + g4 * 8) ^ swz));
                acc2 = __builtin_amdgcn_mfma_f32_16x16x32_bf16(
                    w2f[kc], __builtin_bit_cast(bf16x8, h0), acc2, 0, 0, 0);
                s16x8 h1 = *(const s16x8*)(Hs + ((m * HIDDEN + (kc + 1) * 32 + g4 * 8) ^ swz));
                acc3 = __builtin_amdgcn_mfma_f32_16x16x32_bf16(
                    w2f[kc + 1], __builtin_bit_cast(bf16x8, h1), acc3, 0, 0, 0);
            }
            acc2[0] += acc3[0]; acc2[1] += acc3[1];
            acc2[2] += acc3[2]; acc2[3] += acc3[3];
            int n0 = ntW * 16 + g4 * 4;
            *(f32x4*)(Ss + m * 68 + n0) = acc2;
        }
        __syncthreads();

        // ================= Update phase ====================================
        {
            f32x4 sc = *(const f32x4*)(Ss + urow * 68 + ui);
            f32x4 xo = *(const f32x4*)(Xf + urow * 68 + ui);
            f32x4 xn;
            float pd = 0.f, ps = 0.f;
            #pragma unroll
            for (int c = 0; c < 4; ++c) {
                float means = xo[c] + gg * (2.0f * sc[c] - xo[c]);
                xn[c] = means + sdv * nz[c];
                pd += sc[c] * sc[c];
                ps += sc[c] * nz[c];
            }
            *(f32x4*)(Xf + urow * 68 + ui) = xn;
            *(f32x4*)(out + ubase * OUT_PITCH + (size_t)(s + 1) * ZD + ui) = xn;
            float v = cd * pd + cs * ps;
            v += __shfl_xor(v, 1, 64);
            v += __shfl_xor(v, 2, 64);
            v += __shfl_xor(v, 4, 64);
            v += __shfl_xor(v, 8, 64);
            lw_acc += v;
        }
        __syncthreads();
    }

    // ---- finalize: log_weights and nabla_g ----
    {
        f32x4 x  = *(const f32x4*)(Xf + urow * 68 + ui);
        f32x4 mv = *(const f32x4*)(mus + ui);
        f32x4 ng;
        float part = 0.f;
        #pragma unroll
        for (int c = 0; c < 4; ++c) {
            float d = x[c] - mv[c];
            ng[c] = d - x[c];                          // == -mu (matches ref order)
            part += 0.5f * x[c] * x[c] - 0.5f * d * d; // target_lp - prior_lp
        }
        *(f32x4*)(out + NG_OFF + ubase * ZD + ui) = ng;
        part += __shfl_xor(part, 1, 64);
        part += __shfl_xor(part, 2, 64);
        part += __shfl_xor(part, 4, 64);
        part += __shfl_xor(part, 8, 64);
        if ((tid & 15) == 0) out[LW_OFF + ubase] = lw_acc + part;
    }
}

extern "C" void kernel_launch(void* const* d_in, const int* in_sizes, int n_in,
                              void* d_out, int out_size, void* d_ws, size_t ws_size,
                              hipStream_t stream) {
    const float* r      = (const float*)d_in[0];
    const float* noises = (const float*)d_in[1];
    const float* x0     = (const float*)d_in[2];
    const float* W1     = (const float*)d_in[3];
    const float* b1     = (const float*)d_in[4];
    const float* W2     = (const float*)d_in[5];
    const float* b2     = (const float*)d_in[6];
    const float* bmax   = (const float*)d_in[7];
    const float* bmin   = (const float*)d_in[8];
    const float* mu     = (const float*)d_in[9];
    float* out = (float*)d_out;

    pre_kernel<<<256, 256, 0, stream>>>(r, W1, b1, out);

    // LDS: Xf+Ss (2*32*68*4) + Hs (32*512*2) + w1ts(2048) + mus(256) + tables(5*512)
    const int smem = (32 * 68 * 2 + HIDDEN + 64 + 5 * 128) * 4 + 32 * HIDDEN * 2; // 55040
    sim_kernel<<<256, 512, smem, stream>>>(noises, x0, W1, W2, b2, bmax, bmin, mu, out);
}